// Round 7
// baseline (1005.482 us; speedup 1.0000x reference)
//
#include <hip/hip_runtime.h>
#include <math.h>

#define BB  256
#define TT  2048
#define VV  64
#define DD  50
#define HH  50
#define HIDN 100
#define CHUNK  64
#define NCHUNK (TT / CHUNK)   // 32
#define RPAD   65             // ring row stride (floats): odd -> conflict-free column reads

// [tok][j] = seqFMA_d(embed[tok][d]*Wx[d][j]) + b_rnn[j]; cols 50..63 = 0.
__device__ float g_emWxb[VV * 64];

// ---------------------------------------------------------------------------
// XLA/Eigen fast-tanh, FMA-contracted Horner. BIT-EXACT with the reference
// trajectory (R6 pass). Do not touch: clamp +-7.90531110763549805, fmaf
// Horner, IEEE f32 divide, |x|<4e-4 passthrough.
// ---------------------------------------------------------------------------
__device__ __forceinline__ float xla_tanhf_fma(float x) {
#pragma clang fp contract(off)
  float ax = fabsf(x);
  float cx = fminf(fmaxf(x, -7.90531110763549805f), 7.90531110763549805f);
  float x2 = cx * cx;
  float p = -2.76076847742355e-16f;
  p = fmaf(x2, p, 2.00018790482477e-13f);
  p = fmaf(x2, p, -8.60467152213735e-11f);
  p = fmaf(x2, p, 5.12229709037114e-08f);
  p = fmaf(x2, p, 1.48572235717979e-05f);
  p = fmaf(x2, p, 6.37261928875436e-04f);
  p = fmaf(x2, p, 4.89352455891786e-03f);
  p = cx * p;
  float q = 1.19825839466702e-06f;
  q = fmaf(x2, q, 1.18534705686654e-04f);
  q = fmaf(x2, q, 2.26843463243900e-03f);
  q = fmaf(x2, q, 4.89352518554385e-03f);
  float r = p / q;
  return (ax < 0.0004f) ? x : r;
}

// ---------------------------------------------------------------------------
// K1: xp table, Eigen-gemm bit-emulation (unchanged from passing R6).
// ---------------------------------------------------------------------------
__global__ __launch_bounds__(256) void prep_kernel(
    const float* __restrict__ embed, const float* __restrict__ Wx,
    const float* __restrict__ b_rnn) {
#pragma clang fp contract(off)
  int o = blockIdx.x * 256 + threadIdx.x;
  if (o >= VV * 64) return;
  int v = o >> 6, j = o & 63;
  float val = 0.f;
  if (j < HH) {
    float s = 0.f;
    for (int d = 0; d < DD; ++d)
      s = fmaf(embed[v * DD + d], Wx[d * HH + j], s);
    val = s + b_rnn[j];
  }
  g_emWxb[o] = val;
}

// ---------------------------------------------------------------------------
// Consumer: MLP head for one 64-step chunk, lane = timestep, logit columns
// [LO, LO+NC). Per-element arithmetic IDENTICAL to the R6 head_kernel:
//   acc=0; 50x fmaf ascending i; +b1; relu;  logit=b2; fmaf ascending c.
// h comes from the LDS ring (same f32 bits the producer computed).
// ---------------------------------------------------------------------------
template <int LO, int NC>
__device__ __forceinline__ void consume_chunk(
    const float* hrow,  // &ring[row][0] for this lane (LDS)
    const float* __restrict__ W1, const float* __restrict__ b1,
    const float* __restrict__ W2, const float* __restrict__ b2,
    float* outp) {      // &out[(b*TT + t)*64]
#pragma clang fp contract(off)
  float h[HH];
#pragma unroll
  for (int i = 0; i < HH; ++i) h[i] = hrow[i];   // conflict-free b32 (stride-65 rows)

  float logit[NC];
#pragma unroll
  for (int jj = 0; jj < NC; ++jj) logit[jj] = b2[LO + jj];

  for (int c = 0; c < HIDN; ++c) {
    float acc = 0.f;
#pragma unroll
    for (int i = 0; i < HH; ++i) acc = fmaf(h[i], W1[i * HIDN + c], acc);
    acc += b1[c];
    acc = fmaxf(acc, 0.f);
    const float* w2r = W2 + c * VV + LO;
#pragma unroll
    for (int jj = 0; jj < NC; ++jj) logit[jj] = fmaf(acc, w2r[jj], logit[jj]);
  }

#pragma unroll
  for (int q = 0; q < NC / 4; ++q) {   // LO in {0,24,44}: byte offsets 0/96/176, all 16B-aligned
    float4 v;
    v.x = logit[4 * q + 0];
    v.y = logit[4 * q + 1];
    v.z = logit[4 * q + 2];
    v.w = logit[4 * q + 3];
    *reinterpret_cast<float4*>(outp + LO + 4 * q) = v;
  }
}

// ---------------------------------------------------------------------------
// K2: FUSED producer-consumer. Block = 256 threads (4 waves), 1 block per
// batch row b. Wave 0 runs the serial recurrence (readlane h-broadcast, no
// LDS round-trip, no per-step barrier); waves 1-3 consume 64-step chunks
// from a double-buffered LDS ring and write logits directly (hs never hits
// HBM). One uniform __syncthreads per chunk iteration.
// Chain arithmetic bit-identical to R6 (readlane returns the same bits the
// LDS broadcast did; fmaf order unchanged).
// ---------------------------------------------------------------------------
__global__ __launch_bounds__(256) void fused_kernel(
    const int* __restrict__ inputs, const float* __restrict__ Wh,
    const float* __restrict__ W1, const float* __restrict__ b1,
    const float* __restrict__ W2, const float* __restrict__ b2,
    float* out) {
#pragma clang fp contract(off)
  const int b    = blockIdx.x;
  const int wave = threadIdx.x >> 6;
  const int lane = threadIdx.x & 63;

  __shared__ __align__(16) float emw[VV * 64];        // 16 KB
  __shared__ int toks[TT];                            // 8 KB
  __shared__ float ring[2 * CHUNK][RPAD];             // 33.3 KB

  for (int o = threadIdx.x; o < VV * 64; o += 256) emw[o] = g_emWxb[o];
  const int* rowp = inputs + (size_t)b * TT;
  for (int t = threadIdx.x; t < TT; t += 256) toks[t] = rowp[t];
  __syncthreads();

  // producer state (live only in wave 0)
  float whcol[HH];
  if (wave == 0) {
#pragma unroll
    for (int i = 0; i < HH; ++i)
      whcol[i] = (lane < HH) ? Wh[i * HH + lane] : 0.f;
  }
  float h  = 0.f;
  float xp = emw[toks[0] * 64 + lane];

  for (int it = 0; it <= NCHUNK; ++it) {
    if (wave == 0) {
      if (it < NCHUNK) {
        float* rb = &ring[(it & 1) * CHUNK][0];
        for (int s = 0; s < CHUNK; ++s) {
          const int t = it * CHUNK + s;
          // h broadcast via readlane (two batches of 25 to bound SGPR pressure)
          float acc = 0.f;
#pragma unroll
          for (int i = 0; i < 25; ++i) {
            float hv = __int_as_float(__builtin_amdgcn_readlane(__float_as_int(h), i));
            acc = fmaf(hv, whcol[i], acc);
          }
#pragma unroll
          for (int i = 25; i < HH; ++i) {
            float hv = __int_as_float(__builtin_amdgcn_readlane(__float_as_int(h), i));
            acc = fmaf(hv, whcol[i], acc);
          }
          float pre = xp + acc;
          // prefetch next xp (independent of h)
          int tn = toks[(t + 1 < TT) ? (t + 1) : (TT - 1)];
          float xpn = emw[tn * 64 + lane];

          h = xla_tanhf_fma(pre);
          rb[s * RPAD + lane] = h;   // 2-way bank aliasing = free
          xp = xpn;
        }
      }
    } else {
      if (it >= 1) {
        const int kc = it - 1;
        const float* hrow = &ring[(kc & 1) * CHUNK + lane][0];
        float* outp = out + ((size_t)b * TT + (size_t)kc * CHUNK + lane) * VV;
        if (wave == 1)      consume_chunk<0, 24>(hrow, W1, b1, W2, b2, outp);
        else if (wave == 2) consume_chunk<24, 20>(hrow, W1, b1, W2, b2, outp);
        else                consume_chunk<44, 20>(hrow, W1, b1, W2, b2, outp);
      }
    }
    __syncthreads();  // publish chunk `it`; ring[(it+1)&1] safe to overwrite next iter
  }
}

// ---------------------------------------------------------------------------
extern "C" void kernel_launch(void* const* d_in, const int* in_sizes, int n_in,
                              void* d_out, int out_size, void* d_ws, size_t ws_size,
                              hipStream_t stream) {
  // Map inputs by element-count signature (dict order breaks the Wx/Wh tie).
  const void* p[9] = {nullptr};
  const int want[9] = {BB * TT, VV * DD, DD * HH, HH * HH, HH,
                       HH * HIDN, HIDN, HIDN * VV, VV};
  bool used[32] = {false};
  for (int k = 0; k < 9; ++k)
    for (int i = 0; i < n_in && i < 32; ++i)
      if (!used[i] && in_sizes[i] == want[k]) { p[k] = d_in[i]; used[i] = true; break; }

  const int*   inputs = (const int*)  p[0];
  const float* embed  = (const float*)p[1];
  const float* Wx     = (const float*)p[2];
  const float* Wh     = (const float*)p[3];
  const float* b_rnn  = (const float*)p[4];
  const float* W1     = (const float*)p[5];
  const float* b1     = (const float*)p[6];
  const float* W2     = (const float*)p[7];
  const float* b2     = (const float*)p[8];

  float* out = (float*)d_out;

  prep_kernel<<<(VV * 64 + 255) / 256, 256, 0, stream>>>(embed, Wx, b_rnn);
  fused_kernel<<<BB, 256, 0, stream>>>(inputs, Wh, W1, b1, W2, b2, out);
}